// Round 1
// baseline (64.079 us; speedup 1.0000x reference)
//
#include <hip/hip_runtime.h>
#include <hip/hip_bf16.h>

// GraphLoss: layered lattice DAG (64 layers x 64 nodes, dense bipartite),
// result = sum(w*gold) + logsumexp over all paths of (-path weight).
// Edge layout (from _build_graph, deterministic):
//   e in [0,64): (source -> layer1 node e)
//   e = 64 + l*4096 + a*64 + b: (layer l+1 node a -> layer l+2 node b), l in [0,63)
//   e = 64 + 63*4096 + j: (layer64 node j -> sink)

#define NW 64        // nodes per layer
#define NL 64        // layers
#define PITCH 66     // LDS pitch (<=2-way bank conflict, free)

__global__ void gold_kernel(const int* __restrict__ g, const float* __restrict__ w,
                            float* __restrict__ partial, int E) {
    // graph may arrive as int32 or raw int64 (little-endian). Row 0 is
    // (src=0, dst=1, gold). int32 flat: [0,1,g0,...]; int64 flat-as-int32:
    // [0,0, 1,0, g0,0,...]. So g[1]==1 -> int32, g[1]==0 -> int64.
    const bool is64 = (g[1] == 0);
    const int tid = threadIdx.x;
    float s = 0.f;
    const int stride = gridDim.x * blockDim.x;
    for (int e = blockIdx.x * blockDim.x + tid; e < E; e += stride) {
        int idx = 3 * e + 2;
        int gv = is64 ? g[2 * idx] : g[idx];   // low word holds 0/1
        s += w[e] * (float)gv;
    }
    #pragma unroll
    for (int d = 1; d < 64; d <<= 1) s += __shfl_xor(s, d, 64);
    __shared__ float ls[4];
    const int wv = tid >> 6, ln = tid & 63;
    if (ln == 0) ls[wv] = s;
    __syncthreads();
    if (tid == 0) partial[blockIdx.x] = ls[0] + ls[1] + ls[2] + ls[3];
}

__global__ __launch_bounds__(1024)
void dag_kernel(const float* __restrict__ w, const float* __restrict__ partial,
                float* __restrict__ out) {
    __shared__ float wlds[2][NW * PITCH];
    __shared__ float v[2][NW];

    const int t  = threadIdx.x;
    const int wv = t >> 6;          // wave 0..15
    const int ln = t & 63;          // lane
    const int as = ln & 15;         // a-slot within 16-lane group
    const int b  = 4 * wv + (ln >> 4);  // output node this lane contributes to

    // level 1: v = -w[0..63]
    if (t < NW) v[0][t] = -w[t];

    // stage transition 1 (base 64) into wlds[0]
    float wr[4];
    #pragma unroll
    for (int k = 0; k < 4; ++k) wr[k] = w[64 + t + 1024 * k];
    #pragma unroll
    for (int k = 0; k < 4; ++k) wlds[0][(wv + 16 * k) * PITCH + ln] = wr[k];
    // prefetch transition 2
    #pragma unroll
    for (int k = 0; k < 4; ++k) wr[k] = w[64 + 4096 + t + 1024 * k];
    __syncthreads();

    int cur = 0;
    for (int l = 1; l <= 63; ++l) {
        // compute level l+1 from v[cur], wlds[cur]
        float x[4];
        #pragma unroll
        for (int k = 0; k < 4; ++k) {
            int a = as + 16 * k;
            x[k] = v[cur][a] - wlds[cur][a * PITCH + b];
        }
        float m = fmaxf(fmaxf(x[0], x[1]), fmaxf(x[2], x[3]));
        float s = __expf(x[0] - m) + __expf(x[1] - m) +
                  __expf(x[2] - m) + __expf(x[3] - m);
        #pragma unroll
        for (int d = 1; d < 16; d <<= 1) {
            float om = __shfl_xor(m, d, 64);
            float os = __shfl_xor(s, d, 64);
            float nm = fmaxf(m, om);
            s = __expf(m - nm) * s + __expf(om - nm) * os;
            m = nm;
        }
        if (as == 0) v[cur ^ 1][b] = m + __logf(s);

        // stage transition l+1 into wlds[cur^1]; prefetch transition l+2
        if (l <= 62) {
            #pragma unroll
            for (int k = 0; k < 4; ++k)
                wlds[cur ^ 1][(wv + 16 * k) * PITCH + ln] = wr[k];
            if (l <= 61) {
                #pragma unroll
                for (int k = 0; k < 4; ++k)
                    wr[k] = w[64 + (l + 1) * 4096 + t + 1024 * k];
            }
        }
        __syncthreads();
        cur ^= 1;
    }

    // v[cur] now holds level-64 values; fold sink edges + gold partials (wave 0)
    if (wv == 0) {
        float m = v[cur][ln] - w[64 + 63 * 4096 + ln];
        float s = 1.0f;
        #pragma unroll
        for (int d = 1; d < 64; d <<= 1) {
            float om = __shfl_xor(m, d, 64);
            float os = __shfl_xor(s, d, 64);
            float nm = fmaxf(m, om);
            s = __expf(m - nm) * s + __expf(om - nm) * os;
            m = nm;
        }
        float vs = m + __logf(s);

        float gs = partial[ln] + partial[ln + 64] + partial[ln + 128] + partial[ln + 192];
        #pragma unroll
        for (int d = 1; d < 64; d <<= 1) gs += __shfl_xor(gs, d, 64);

        if (ln == 0) out[0] = gs + vs;
    }
}

extern "C" void kernel_launch(void* const* d_in, const int* in_sizes, int n_in,
                              void* d_out, int out_size, void* d_ws, size_t ws_size,
                              hipStream_t stream) {
    const int*   g = (const int*)d_in[0];
    const float* w = (const float*)d_in[1];
    float* out     = (float*)d_out;
    float* partial = (float*)d_ws;   // 256 floats
    const int E = in_sizes[0] / 3;   // 258176

    gold_kernel<<<256, 256, 0, stream>>>(g, w, partial, E);
    dag_kernel<<<1, 1024, 0, stream>>>(w, partial, out);
}

// Round 2
// 39.195 us; speedup vs baseline: 1.6349x; 1.6349x over previous
//
#include <hip/hip_runtime.h>
#include <hip/hip_bf16.h>

// GraphLoss: layered lattice DAG (64 layers x 64 nodes, dense bipartite).
// result = sum(w*gold) + logsumexp over all source->sink paths of (-path weight).
// Key factorization: lsexp_a(v[a]-W[a][b]) = z0 + log( sum_a exp(v[a]-z0) * exp(-W[a][b]) )
// -> exp(-W) precomputed in parallel once; the 63-step sequential chain is 63
//    plain 64x64 matvecs on one wave (lane = output node b).
//
// Edge layout (deterministic from _build_graph):
//   e in [0,64): source -> layer1 node e
//   e = 64 + l*4096 + a*64 + b: layer(l+1) node a -> layer(l+2) node b, l in [0,63)
//   e = 258112 + j: layer64 node j -> sink

#define LVLS 63
#define WEXP_FLOATS (63 * 4096)     // 258048
#define SINK_BASE   (64 + 63 * 4096) // 258112
#define NPB 512                      // prep blocks (gold partials)

// ---------------------------------------------------------------------------
// prep: wexp[o] = exp(-w[e(o)]) in seq-kernel-friendly interleaved layout
//       o = l*4096 + q*256 + b*4 + j  <->  a = 4q+j, e = 64 + l*4096 + a*64 + b
//       (so seq lane b, chunk k reads float4 at (l*16+k)*64 + b : coalesced)
// also: block-level partial sums of w*gold.
__global__ __launch_bounds__(512)
void prep_kernel(const int* __restrict__ g, const float* __restrict__ w,
                 float* __restrict__ wexp, float* __restrict__ partial, int E) {
    const int t = blockIdx.x * blockDim.x + threadIdx.x;
    if (t < WEXP_FLOATS) {
        const int j = t & 3;
        const int b = (t >> 2) & 63;
        const int q = (t >> 8) & 15;
        const int l = t >> 12;
        const int a = 4 * q + j;
        const int e = 64 + l * 4096 + a * 64 + b;
        wexp[t] = __expf(-w[e]);
    }
    // gold = sum w[e]*gold[e], grid-stride. graph may be int32 or int64 words.
    const bool is64 = (g[1] == 0);
    float s = 0.f;
    const int stride = gridDim.x * blockDim.x;
    for (int e = t; e < E; e += stride) {
        const int idx = 3 * e + 2;
        const int gv = is64 ? g[2 * idx] : g[idx];
        s += w[e] * (float)gv;
    }
    #pragma unroll
    for (int d = 1; d < 64; d <<= 1) s += __shfl_xor(s, d, 64);
    __shared__ float ls[8];
    const int wv = threadIdx.x >> 6, ln = threadIdx.x & 63;
    if (ln == 0) ls[wv] = s;
    __syncthreads();
    if (threadIdx.x == 0) {
        float tt = 0.f;
        #pragma unroll
        for (int i = 0; i < 8; ++i) tt += ls[i];
        partial[blockIdx.x] = tt;
    }
}

// ---------------------------------------------------------------------------
// seq: single wave. lane = node b. 63 matvecs y[b] = sum_a u[a]*Wexp[a][b].
// W streamed into registers 2 levels ahead (3 rotating 16xfloat4 buffers).
__global__ __launch_bounds__(64, 1)
void seq_kernel(const float* __restrict__ w, const float* __restrict__ wexp,
                const float* __restrict__ partial, float* __restrict__ out) {
    __shared__ float ulds[64];
    const int lane = threadIdx.x;
    const float4* wx = (const float4*)wexp;   // element (l*16+k)*64 + lane
    const float4* uq4 = (const float4*)ulds;

    float z = -w[lane];     // layer-1 value (rebased); absolute offset in Csum
    float Csum = 0.f;

    float4 wb0[16], wb1[16], wb2[16];

#define LOADBUF(BUF, L)                                                        \
    _Pragma("unroll")                                                          \
    for (int k = 0; k < 16; ++k) BUF[k] = wx[((((L) * 16) + k) << 6) + lane];

#define BODY(L, CUR, NX2) {                                                    \
    if ((L) + 2 < LVLS) { LOADBUF(NX2, (L) + 2) }                              \
    float z0 = __int_as_float(__builtin_amdgcn_readfirstlane(__float_as_int(z)));\
    Csum += z0;                                                                \
    ulds[lane] = __expf(z - z0);                                               \
    __syncthreads();                                                           \
    float a0 = 0.f, a1 = 0.f, a2 = 0.f, a3 = 0.f;                              \
    _Pragma("unroll")                                                          \
    for (int k = 0; k < 16; ++k) {                                             \
        float4 uq = uq4[k]; float4 wv = CUR[k];                                \
        a0 += uq.x * wv.x; a1 += uq.y * wv.y;                                  \
        a2 += uq.z * wv.z; a3 += uq.w * wv.w;                                  \
    }                                                                          \
    z = __logf((a0 + a1) + (a2 + a3));                                         \
    __syncthreads();                                                           \
}

    LOADBUF(wb0, 0)
    LOADBUF(wb1, 1)

    #pragma unroll 1
    for (int lt = 0; lt < 63; lt += 3) {
        BODY(lt + 0, wb0, wb2)
        BODY(lt + 1, wb1, wb0)
        BODY(lt + 2, wb2, wb1)
    }

    // sink fold: lsexp_b( Csum + z[b] - w_sink[b] )
    float m = z + Csum - w[SINK_BASE + lane];
    float s = 1.0f;
    #pragma unroll
    for (int d = 1; d < 64; d <<= 1) {
        float om = __shfl_xor(m, d, 64);
        float os = __shfl_xor(s, d, 64);
        float nm = fmaxf(m, om);
        s = __expf(m - nm) * s + __expf(om - nm) * os;
        m = nm;
    }
    const float vsink = m + __logf(s);

    // gold partial fold (512 partials)
    float gs = 0.f;
    #pragma unroll
    for (int i = 0; i < 8; ++i) gs += partial[lane + (i << 6)];
    #pragma unroll
    for (int d = 1; d < 64; d <<= 1) gs += __shfl_xor(gs, d, 64);

    if (lane == 0) out[0] = gs + vsink;
}

extern "C" void kernel_launch(void* const* d_in, const int* in_sizes, int n_in,
                              void* d_out, int out_size, void* d_ws, size_t ws_size,
                              hipStream_t stream) {
    const int*   g = (const int*)d_in[0];
    const float* w = (const float*)d_in[1];
    float* out     = (float*)d_out;
    float* wexp    = (float*)d_ws;                  // 258048 floats
    float* partial = wexp + WEXP_FLOATS;            // 512 floats
    const int E = in_sizes[0] / 3;                  // 258176

    prep_kernel<<<NPB, 512, 0, stream>>>(g, w, wexp, partial, E);
    seq_kernel<<<1, 64, 0, stream>>>(w, wexp, partial, out);
}

// Round 5
// 34.662 us; speedup vs baseline: 1.8487x; 1.1308x over previous
//
#include <hip/hip_runtime.h>
#include <hip/hip_bf16.h>
#include <cstdint>

// GraphLoss: layered lattice DAG (64 layers x 64 nodes, dense bipartite).
// result = sum(w*gold) + logsumexp over all source->sink paths of (-path weight).
// lsexp_a(v[a]-W[a][b]) = z0 + log( sum_a exp(v[a]-z0) * exp(-W[a][b]) )
// exp(-W) precomputed in prep as PACKED BF16 PAIRS (halves regs + traffic);
// the 63-step chain is 63 64x64 matvecs on ONE wave (lane = output node b),
// W hand-prefetched into registers via inline-asm global_load_dwordx4.
//
// R3/R4 lesson: VGPR file is hard-capped at 256/wave; 128+ VGPR of f32
// buffers + scheduler temps hit the cap -> allocator spilled asm-output regs
// with loads still in flight (garbage). Fix: bf16-packed buffers (64 VGPR
// total) + vmcnt(0)-only draining (immune to stray compiler VMEM) + a
// data-dependency pin so consumers can't be hoisted above the wait.
//
// Edge layout (deterministic from _build_graph):
//   e in [0,64): source -> layer1 node e
//   e = 64 + l*4096 + a*64 + b: layer(l+1) node a -> layer(l+2) node b, l<63
//   e = 258112 + j: layer64 node j -> sink

typedef float v2f   __attribute__((ext_vector_type(2)));
typedef float f32x4 __attribute__((ext_vector_type(4)));
typedef unsigned int u32x4 __attribute__((ext_vector_type(4)));

#define LVLS 63
#define NPACK (63 * 2048)            // packed u32 count = 129024
#define SINK_BASE (64 + 63 * 4096)   // 258112
#define NPB 256

// ---------------------------------------------------------------------------
// prep: wpk[f] packs bf16(exp(-w[e0])) | bf16(exp(-w[e1]))<<16 where
//   f = ((l*8 + c)*64 + b)*4 + d,  a0 = 8c+2d,  e0 = 64 + l*4096 + a0*64 + b,
//   e1 = e0 + 64.  Seq lane b reads uint4 at byte (l*8+c)*1024 + b*16:
//   components d=0..3 = weight pairs (a0, a0+1). Fully coalesced.
// plus block partials of sum(w*gold).
__global__ __launch_bounds__(512)
void prep_kernel(const int* __restrict__ g, const float* __restrict__ w,
                 unsigned int* __restrict__ wpk, float* __restrict__ partial, int E) {
    const int f = blockIdx.x * blockDim.x + threadIdx.x;
    if (f < NPACK) {
        const int d = f & 3;
        const int b = (f >> 2) & 63;
        const int c = (f >> 8) & 7;
        const int l = f >> 11;
        const int a0 = 8 * c + 2 * d;
        const int e0 = 64 + l * 4096 + a0 * 64 + b;
        const float x0 = __expf(-w[e0]);
        const float x1 = __expf(-w[e0 + 64]);
        uint32_t u0 = __float_as_uint(x0); u0 = (u0 + 0x7fffu + ((u0 >> 16) & 1u)) >> 16;
        uint32_t u1 = __float_as_uint(x1); u1 = (u1 + 0x7fffu + ((u1 >> 16) & 1u)) >> 16;
        wpk[f] = u0 | (u1 << 16);
    }
    // gold = sum w[e]*gold[e]; graph may be int32 or int64 words.
    const bool is64 = (g[1] == 0);
    float s = 0.f;
    const int stride = gridDim.x * blockDim.x;
    for (int e = f; e < E; e += stride) {
        const int idx = 3 * e + 2;
        const int gv = is64 ? g[2 * idx] : g[idx];
        s += w[e] * (float)gv;
    }
    #pragma unroll
    for (int dd = 1; dd < 64; dd <<= 1) s += __shfl_xor(s, dd, 64);
    __shared__ float ls[8];
    const int wv = threadIdx.x >> 6, ln = threadIdx.x & 63;
    if (ln == 0) ls[wv] = s;
    __syncthreads();
    if (threadIdx.x == 0) {
        float tt = 0.f;
        #pragma unroll
        for (int i = 0; i < 8; ++i) tt += ls[i];
        partial[blockIdx.x] = tt;
    }
}

// ---------------------------------------------------------------------------
// seq: single wave, lane = node b. 63 matvecs y[b] = sum_a u[a]*Wexp[a][b].
__global__ __launch_bounds__(64, 1)
void seq_kernel(const float* __restrict__ w, const unsigned int* __restrict__ wpk,
                const float* __restrict__ partial, float* __restrict__ out) {
    __shared__ f32x4 uldsv[16];           // u[64], 16B-aligned
    float* ulds = (float*)uldsv;
    const int lane = threadIdx.x;

    // compiler-visible loads, pinned complete before the asm stream
    float z = -w[lane];
    float wsink = w[SINK_BASE + lane];
    float gs = 0.f;
    #pragma unroll
    for (int i = 0; i < 4; ++i) gs += partial[lane + (i << 6)];
    asm volatile("" : "+v"(z), "+v"(wsink), "+v"(gs));

    const uint32_t voff = (uint32_t)lane * 16u;
    uintptr_t bcur = (uintptr_t)wpk;      // wave-uniform -> SGPR

    u32x4 wb0[8], wb1[8];
    float Csum = 0.f;

#define LD1(DST, B, OFFSTR)                                                    \
    asm volatile("global_load_dwordx4 %0, %1, %2 offset:" OFFSTR               \
                 : "=v"(DST) : "v"(voff), "s"(B))

#define ISSUE(BUF) do {                                                        \
    uintptr_t bA = bcur, bB = bcur + 4096u;                                    \
    LD1(BUF[0], bA, "0");    LD1(BUF[1], bA, "1024");                          \
    LD1(BUF[2], bA, "2048"); LD1(BUF[3], bA, "3072");                          \
    LD1(BUF[4], bB, "0");    LD1(BUF[5], bB, "1024");                          \
    LD1(BUF[6], bB, "2048"); LD1(BUF[7], bB, "3072");                          \
    bcur += 8192u;                                                             \
} while (0)

// vmcnt(0): drains EVERYTHING (robust to any stray compiler VMEM). The pin
// makes all consumers of BUF data-depend on an asm ordered after the wait.
#define WAITPIN(BUF) do {                                                      \
    asm volatile("s_waitcnt vmcnt(0)" ::: "memory");                           \
    __builtin_amdgcn_sched_barrier(0);                                         \
    asm volatile("" : "+v"(BUF[0]), "+v"(BUF[1]), "+v"(BUF[2]), "+v"(BUF[3]), \
                      "+v"(BUF[4]), "+v"(BUF[5]), "+v"(BUF[6]), "+v"(BUF[7])); \
} while (0)

// Invariant at BODY(CUR,NXT,L) entry: CUR holds level L, already drained+pinned.
#define BODY(CUR, NXT, L) {                                                    \
    if ((L) < 62) ISSUE(NXT);                                                  \
    float z0 = __int_as_float(__builtin_amdgcn_readfirstlane(__float_as_int(z)));\
    Csum += z0;                                                                \
    ulds[lane] = __expf(z - z0);                                               \
    v2f acc0 = {0.f, 0.f}, acc1 = {0.f, 0.f};                                  \
    _Pragma("unroll")                                                          \
    for (int c = 0; c < 8; ++c) {                                              \
        f32x4 ua = uldsv[2 * c];                                               \
        f32x4 ub = uldsv[2 * c + 1];                                           \
        u32x4 wc = CUR[c];                                                     \
        v2f w0, w1, w2, w3, u01, u23, u45, u67;                                \
        w0[0] = __uint_as_float(wc[0] << 16);                                  \
        w0[1] = __uint_as_float(wc[0] & 0xffff0000u);                          \
        w1[0] = __uint_as_float(wc[1] << 16);                                  \
        w1[1] = __uint_as_float(wc[1] & 0xffff0000u);                          \
        w2[0] = __uint_as_float(wc[2] << 16);                                  \
        w2[1] = __uint_as_float(wc[2] & 0xffff0000u);                          \
        w3[0] = __uint_as_float(wc[3] << 16);                                  \
        w3[1] = __uint_as_float(wc[3] & 0xffff0000u);                          \
        u01[0] = ua[0]; u01[1] = ua[1]; u23[0] = ua[2]; u23[1] = ua[3];        \
        u45[0] = ub[0]; u45[1] = ub[1]; u67[0] = ub[2]; u67[1] = ub[3];        \
        acc0 = __builtin_elementwise_fma(w0, u01, acc0);                       \
        acc1 = __builtin_elementwise_fma(w1, u23, acc1);                       \
        acc0 = __builtin_elementwise_fma(w2, u45, acc0);                       \
        acc1 = __builtin_elementwise_fma(w3, u67, acc1);                       \
    }                                                                          \
    v2f at = acc0 + acc1;                                                      \
    z = __logf(at[0] + at[1]);                                                 \
    if ((L) < 62) WAITPIN(NXT);                                                \
}

    ISSUE(wb0);        // level 0
    WAITPIN(wb0);      // one-time full-latency stall

    #pragma unroll 1
    for (int it = 0; it < 31; ++it) {
        BODY(wb0, wb1, 2 * it)       // consumes L=2it,  issues+drains 2it+1
        BODY(wb1, wb0, 2 * it + 1)   // consumes 2it+1,  issues+drains 2it+2
    }
    BODY(wb0, wb1, 62)               // tail: no issue, no wait

    // sink fold: lsexp_b( Csum + z[b] - w_sink[b] )
    float m = z + Csum - wsink;
    float s = 1.0f;
    #pragma unroll
    for (int d = 1; d < 64; d <<= 1) {
        float om = __shfl_xor(m, d, 64);
        float os = __shfl_xor(s, d, 64);
        float nm = fmaxf(m, om);
        s = __expf(m - nm) * s + __expf(om - nm) * os;
        m = nm;
    }
    const float vsink = m + __logf(s);

    #pragma unroll
    for (int d = 1; d < 64; d <<= 1) gs += __shfl_xor(gs, d, 64);

    if (lane == 0) out[0] = gs + vsink;
}

extern "C" void kernel_launch(void* const* d_in, const int* in_sizes, int n_in,
                              void* d_out, int out_size, void* d_ws, size_t ws_size,
                              hipStream_t stream) {
    const int*   g = (const int*)d_in[0];
    const float* w = (const float*)d_in[1];
    float* out     = (float*)d_out;
    unsigned int* wpk = (unsigned int*)d_ws;        // 129024 u32
    float* partial = (float*)(wpk + NPACK);         // 256 floats
    const int E = in_sizes[0] / 3;                  // 258176

    prep_kernel<<<NPB, 512, 0, stream>>>(g, w, wpk, partial, E);
    seq_kernel<<<1, 64, 0, stream>>>(w, wpk, partial, out);
}

// Round 7
// 33.786 us; speedup vs baseline: 1.8966x; 1.0259x over previous
//
#include <hip/hip_runtime.h>
#include <hip/hip_bf16.h>
#include <cstdint>

// GraphLoss: layered lattice DAG (64 layers x 64 nodes, dense bipartite).
// result = sum(w*gold) + logsumexp over all source->sink paths of (-path weight).
// lsexp_a(v[a]-W[a][b]) = z0 + log( sum_a exp(v[a]-z0) * exp(-W[a][b]) )
// exp(-W) precomputed in prep as PACKED BF16 PAIRS; the 63-step chain is 63
// 64x64 matvecs on ONE wave (lane = output node b), W hand-prefetched into
// registers (inline-asm global_load_dwordx4, 3 rotating buffers, counted vmcnt).
//
// R3/R4/R6 bug class (all failures): exiting a region with asm loads IN
// FLIGHT whose target regs the allocator may reuse; non-volatile VALU can
// hoist above a volatile s_waitcnt, so a late-landing (dummy/tail) load
// smashes a reused physreg. Fix: NO dummy loads; peel the last 3 bodies with
// exact waits 16/8/0 so the loop exits with ZERO loads in flight; every load's
// target stays live until a "+v" PIN read after its drain.
// Compute path is byte-for-byte the R5-proven one (absmax 0.0).
//
// Edge layout (deterministic from _build_graph):
//   e in [0,64): source -> layer1 node e
//   e = 64 + l*4096 + a*64 + b: layer(l+1) node a -> layer(l+2) node b, l<63
//   e = 258112 + j: layer64 node j -> sink

typedef float v2f   __attribute__((ext_vector_type(2)));
typedef float f32x4 __attribute__((ext_vector_type(4)));
typedef unsigned int u32x4 __attribute__((ext_vector_type(4)));

#define LVLS 63
#define NPACK (63 * 2048)            // packed u32 count = 129024 (8KB/level)
#define SINK_BASE (64 + 63 * 4096)   // 258112
#define NPB 256

// ---------------------------------------------------------------------------
// prep: wpk[f] packs bf16(exp(-w[e0])) | bf16(exp(-w[e1]))<<16 where
//   f = ((l*8 + c)*64 + b)*4 + d,  a0 = 8c+2d,  e0 = 64 + l*4096 + a0*64 + b,
//   e1 = e0 + 64.  Seq lane b reads uint4 at byte (l*8+c)*1024 + b*16. Coalesced.
// plus block partials of sum(w*gold).   (unchanged from R5 — proven)
__global__ __launch_bounds__(512)
void prep_kernel(const int* __restrict__ g, const float* __restrict__ w,
                 unsigned int* __restrict__ wpk, float* __restrict__ partial, int E) {
    const int f = blockIdx.x * blockDim.x + threadIdx.x;
    if (f < NPACK) {
        const int d = f & 3;
        const int b = (f >> 2) & 63;
        const int c = (f >> 8) & 7;
        const int l = f >> 11;
        const int a0 = 8 * c + 2 * d;
        const int e0 = 64 + l * 4096 + a0 * 64 + b;
        const float x0 = __expf(-w[e0]);
        const float x1 = __expf(-w[e0 + 64]);
        uint32_t u0 = __float_as_uint(x0); u0 = (u0 + 0x7fffu + ((u0 >> 16) & 1u)) >> 16;
        uint32_t u1 = __float_as_uint(x1); u1 = (u1 + 0x7fffu + ((u1 >> 16) & 1u)) >> 16;
        wpk[f] = u0 | (u1 << 16);
    }
    const bool is64 = (g[1] == 0);
    float s = 0.f;
    const int stride = gridDim.x * blockDim.x;
    for (int e = f; e < E; e += stride) {
        const int idx = 3 * e + 2;
        const int gv = is64 ? g[2 * idx] : g[idx];
        s += w[e] * (float)gv;
    }
    #pragma unroll
    for (int dd = 1; dd < 64; dd <<= 1) s += __shfl_xor(s, dd, 64);
    __shared__ float ls[8];
    const int wv = threadIdx.x >> 6, ln = threadIdx.x & 63;
    if (ln == 0) ls[wv] = s;
    __syncthreads();
    if (threadIdx.x == 0) {
        float tt = 0.f;
        #pragma unroll
        for (int i = 0; i < 8; ++i) tt += ls[i];
        partial[blockIdx.x] = tt;
    }
}

// ---------------------------------------------------------------------------
// seq: single wave, lane = node b. 63 matvecs y[b] = sum_a u[a]*Wexp[a][b].
__global__ __launch_bounds__(64, 1)
void seq_kernel(const float* __restrict__ w, const unsigned int* __restrict__ wpk,
                const float* __restrict__ partial, float* __restrict__ out) {
    __shared__ f32x4 uldsv[16];           // u[64], 16B-aligned
    float* ulds = (float*)uldsv;
    const int lane = threadIdx.x;

    // compiler-visible loads, pinned complete before the asm stream
    float z = -w[lane];
    float wsink = w[SINK_BASE + lane];
    float gs = 0.f;
    #pragma unroll
    for (int i = 0; i < 4; ++i) gs += partial[lane + (i << 6)];
    asm volatile("" : "+v"(z), "+v"(wsink), "+v"(gs));

    const uint32_t voff = (uint32_t)lane * 16u;
    uintptr_t bcur = (uintptr_t)wpk;      // wave-uniform -> SGPR pair

    u32x4 wb0[8], wb1[8], wb2[8];
    float Csum = 0.f;

#define LD1(DST, B, OFFSTR)                                                    \
    asm volatile("global_load_dwordx4 %0, %1, %2 offset:" OFFSTR               \
                 : "=v"(DST) : "v"(voff), "s"(B))

#define ISSUE(BUF) do {                                                        \
    uintptr_t bA = bcur, bB = bcur + 4096u;                                    \
    LD1(BUF[0], bA, "0");    LD1(BUF[1], bA, "1024");                          \
    LD1(BUF[2], bA, "2048"); LD1(BUF[3], bA, "3072");                          \
    LD1(BUF[4], bB, "0");    LD1(BUF[5], bB, "1024");                          \
    LD1(BUF[6], bB, "2048"); LD1(BUF[7], bB, "3072");                          \
    bcur += 8192u;                                                             \
} while (0)

#define PIN8(BUF)                                                              \
    asm volatile("" : "+v"(BUF[0]), "+v"(BUF[1]), "+v"(BUF[2]), "+v"(BUF[3]), \
                      "+v"(BUF[4]), "+v"(BUF[5]), "+v"(BUF[6]), "+v"(BUF[7]))

// R5-proven compute core (absmax 0.0): f32 u broadcast through LDS,
// bf16-pair W unpack + packed fma.
#define COMPUTE(CUR) {                                                         \
    float z0 = __int_as_float(__builtin_amdgcn_readfirstlane(__float_as_int(z)));\
    Csum += z0;                                                                \
    ulds[lane] = __expf(z - z0);                                               \
    v2f acc0 = {0.f, 0.f}, acc1 = {0.f, 0.f};                                  \
    _Pragma("unroll")                                                          \
    for (int c = 0; c < 8; ++c) {                                              \
        f32x4 ua = uldsv[2 * c];                                               \
        f32x4 ub = uldsv[2 * c + 1];                                           \
        u32x4 wc = CUR[c];                                                     \
        v2f w0, w1, w2, w3, u01, u23, u45, u67;                                \
        w0[0] = __uint_as_float(wc[0] << 16);                                  \
        w0[1] = __uint_as_float(wc[0] & 0xffff0000u);                          \
        w1[0] = __uint_as_float(wc[1] << 16);                                  \
        w1[1] = __uint_as_float(wc[1] & 0xffff0000u);                          \
        w2[0] = __uint_as_float(wc[2] << 16);                                  \
        w2[1] = __uint_as_float(wc[2] & 0xffff0000u);                          \
        w3[0] = __uint_as_float(wc[3] << 16);                                  \
        w3[1] = __uint_as_float(wc[3] & 0xffff0000u);                          \
        u01[0] = ua[0]; u01[1] = ua[1]; u23[0] = ua[2]; u23[1] = ua[3];        \
        u45[0] = ub[0]; u45[1] = ub[1]; u67[0] = ub[2]; u67[1] = ub[3];        \
        acc0 = __builtin_elementwise_fma(w0, u01, acc0);                       \
        acc1 = __builtin_elementwise_fma(w1, u23, acc1);                       \
        acc0 = __builtin_elementwise_fma(w2, u45, acc0);                       \
        acc1 = __builtin_elementwise_fma(w3, u67, acc1);                       \
    }                                                                          \
    v2f at = acc0 + acc1;                                                      \
    z = __logf(at[0] + at[1]);                                                 \
}

// Steady-state body: ISSUE(L+2) -> 24 outstanding; vmcnt(16) drains exactly
// the oldest 8 (= CUR's level). sched_barriers pin ISSUE above and consumers
// below; PIN8 makes consumption data-depend on a post-wait volatile asm.
#define BODYI(CUR, NX2) {                                                      \
    ISSUE(NX2);                                                                \
    __builtin_amdgcn_sched_barrier(0);                                         \
    asm volatile("s_waitcnt vmcnt(16)" ::: "memory");                          \
    __builtin_amdgcn_sched_barrier(0);                                         \
    PIN8(CUR);                                                                 \
    COMPUTE(CUR)                                                               \
}

// Tail body: no issue; exact residual count N (8 then 0).
#define BODYW(CUR, NSTR) {                                                     \
    asm volatile("s_waitcnt vmcnt(" NSTR ")" ::: "memory");                    \
    __builtin_amdgcn_sched_barrier(0);                                         \
    PIN8(CUR);                                                                 \
    COMPUTE(CUR)                                                               \
}

    ISSUE(wb0);   // level 0
    ISSUE(wb1);   // level 1

    // bodies 0..59: 20 iterations x 3-buffer rotation
    #pragma unroll 1
    for (int it = 0; it < 20; ++it) {
        BODYI(wb0, wb2)   // consume 3it,   issue 3it+2
        BODYI(wb1, wb0)   // consume 3it+1, issue 3it+3
        BODYI(wb2, wb1)   // consume 3it+2, issue 3it+4
    }
    // peeled tail: bodies 60..62; after body 62 ZERO loads in flight
    BODYI(wb0, wb2)       // consume L60, issue L62 (real, last issue)
    BODYW(wb1, "8")       // consume L61
    BODYW(wb2, "0")       // consume L62

    // sink fold: lsexp_b( Csum + z[b] - w_sink[b] )
    float m = z + Csum - wsink;
    float s = 1.0f;
    #pragma unroll
    for (int d = 1; d < 64; d <<= 1) {
        float om = __shfl_xor(m, d, 64);
        float os = __shfl_xor(s, d, 64);
        float nm = fmaxf(m, om);
        s = __expf(m - nm) * s + __expf(om - nm) * os;
        m = nm;
    }
    const float vsink = m + __logf(s);

    #pragma unroll
    for (int d = 1; d < 64; d <<= 1) gs += __shfl_xor(gs, d, 64);

    if (lane == 0) out[0] = gs + vsink;
}

extern "C" void kernel_launch(void* const* d_in, const int* in_sizes, int n_in,
                              void* d_out, int out_size, void* d_ws, size_t ws_size,
                              hipStream_t stream) {
    const int*   g = (const int*)d_in[0];
    const float* w = (const float*)d_in[1];
    float* out     = (float*)d_out;
    unsigned int* wpk = (unsigned int*)d_ws;        // 129024 u32
    float* partial = (float*)(wpk + NPACK);         // 256 floats
    const int E = in_sizes[0] / 3;                  // 258176

    prep_kernel<<<NPB, 512, 0, stream>>>(g, w, wpk, partial, E);
    seq_kernel<<<1, 64, 0, stream>>>(w, wpk, partial, out);
}

// Round 8
// 30.703 us; speedup vs baseline: 2.0871x; 1.1004x over previous
//
#include <hip/hip_runtime.h>
#include <hip/hip_bf16.h>
#include <cstdint>

// GraphLoss: layered lattice DAG (64 layers x 64 nodes, dense bipartite).
// result = sum(w*gold) + logsumexp over all source->sink paths of (-path weight).
// lsexp_a(v[a]-W[a][b]) = s0 + log( sum_a exp(v[a]-s0) * exp(-W[a][b]) )
// exp(-W) precomputed (prep) as packed bf16 pairs in a 4-wave fragment layout.
// seq: 256 threads / 4 waves. Wave wv owns output nodes b=16wv..16wv+15;
// lane l computes the 16-term k-chunk (kc=l>>4) partial for b=16wv+(l&15),
// folded via shfl_xor(16,32). Per level per lane: 2 global dwordx4 (4-deep
// hand prefetch, counted vmcnt), 4 LDS b128 u-reads, 8 pk_fma, 1 exp, 1 log.
// Sync: raw s_barrier + lgkmcnt(0) ONLY (never __syncthreads -> would drain
// vmcnt and kill the prefetch pipeline). Shift s0 = previous level's z[0]
// via double-buffered LDS scalar; z stays absolute (shift cancels exactly).
//
// Hazard rules from R3-R7: no dummy loads; peeled tail with exact waits
// 6/4/2/0 so ZERO loads in flight at loop exit; "+v" PIN after each wait;
// sched_barrier(0) after waits; compiler-visible global loads only at init,
// pinned complete before the asm stream.
//
// Edge layout: e = 64 + l*4096 + a*64 + b (layer l+1 node a -> layer l+2 node b)

typedef float v2f   __attribute__((ext_vector_type(2)));
typedef float f32x4 __attribute__((ext_vector_type(4)));
typedef unsigned int u32x4 __attribute__((ext_vector_type(4)));

#define LVLS 63
#define NPACK (63 * 2048)            // packed u32 words (8KB/level)
#define SINK_BASE (64 + 63 * 4096)   // 258112
#define NPB 256

// ---------------------------------------------------------------------------
// prep: word f = L*2048 + h*1024 + t*4 + q  (t = seq thread id 0..255)
//   wv=t>>6, ls=t&63, kc=ls>>4, b=16wv+(ls&15), j2=4h+q, k=16kc+2*j2
//   packs bf16(exp(-w[e0])) | bf16(exp(-w[e0+64]))<<16, e0 = 64+L*4096+k*64+b.
//   Seq thread t reads its 2 quads at bytes L*8192 + t*16 and +4096. Coalesced.
// plus block partials of sum(w*gold).
__global__ __launch_bounds__(512)
void prep_kernel(const int* __restrict__ g, const float* __restrict__ w,
                 unsigned int* __restrict__ wpk, float* __restrict__ partial, int E) {
    const int f = blockIdx.x * blockDim.x + threadIdx.x;
    if (f < NPACK) {
        const int L = f >> 11;
        const int r = f & 2047;
        const int h = (r >> 10) & 1;
        const int t = (r >> 2) & 255;
        const int q = r & 3;
        const int wvp = t >> 6, ls = t & 63;
        const int kcp = ls >> 4, bp = 16 * wvp + (ls & 15);
        const int j2 = 4 * h + q;
        const int k = 16 * kcp + 2 * j2;
        const int e0 = 64 + L * 4096 + k * 64 + bp;
        const float x0 = __expf(-w[e0]);
        const float x1 = __expf(-w[e0 + 64]);
        uint32_t u0 = __float_as_uint(x0); u0 = (u0 + 0x7fffu + ((u0 >> 16) & 1u)) >> 16;
        uint32_t u1 = __float_as_uint(x1); u1 = (u1 + 0x7fffu + ((u1 >> 16) & 1u)) >> 16;
        wpk[f] = u0 | (u1 << 16);
    }
    const bool is64 = (g[1] == 0);
    float s = 0.f;
    const int stride = gridDim.x * blockDim.x;
    for (int e = f; e < E; e += stride) {
        const int idx = 3 * e + 2;
        const int gv = is64 ? g[2 * idx] : g[idx];
        s += w[e] * (float)gv;
    }
    #pragma unroll
    for (int dd = 1; dd < 64; dd <<= 1) s += __shfl_xor(s, dd, 64);
    __shared__ float lsm[8];
    const int wv = threadIdx.x >> 6, ln = threadIdx.x & 63;
    if (ln == 0) lsm[wv] = s;
    __syncthreads();
    if (threadIdx.x == 0) {
        float tt = 0.f;
        #pragma unroll
        for (int i = 0; i < 8; ++i) tt += lsm[i];
        partial[blockIdx.x] = tt;
    }
}

// ---------------------------------------------------------------------------
__global__ __launch_bounds__(256, 1)
void seq_kernel(const float* __restrict__ w, const unsigned int* __restrict__ wpk,
                const float* __restrict__ partial, float* __restrict__ out) {
    __shared__ __align__(16) float ubuf[2][64];   // double-buffered u
    __shared__ float zls[2];                      // double-buffered shift source
    __shared__ float slds[64];                    // sink-fold staging
    const int tid = threadIdx.x;
    const int wv = tid >> 6, l = tid & 63;
    const int kc = l >> 4;
    const int bb = 16 * wv + (l & 15);            // this lane's output node

    // init loads (compiler-visible), pinned complete before the asm stream
    float zr = -w[bb];                            // layer-1 z (absolute)
    float wsink = w[SINK_BASE + bb];
    float gs = 0.f;
    #pragma unroll
    for (int i = 0; i < 4; ++i) gs += partial[l + (i << 6)];
    asm volatile("" : "+v"(zr), "+v"(wsink), "+v"(gs));

    float S = 0.f;                                // shift baked into current ubuf
    if (l < 16) ubuf[0][bb] = __expf(zr - S);     // u_1 = exp(z_1)
    if (tid == 0) zls[0] = zr;                    // z_1[0]
    asm volatile("s_waitcnt lgkmcnt(0)" ::: "memory");
    __builtin_amdgcn_s_barrier();

    const uint32_t voff  = (uint32_t)tid * 16u;
    const uint32_t voff2 = voff + 4096u;
    uintptr_t bcur = (uintptr_t)wpk;

    u32x4 q0a, q0b, q1a, q1b, q2a, q2b, q3a, q3b;

#define LD1(DST, VO)                                                           \
    asm volatile("global_load_dwordx4 %0, %1, %2"                              \
                 : "=v"(DST) : "v"(VO), "s"(bcur))

#define ISSUE(QA, QB) do { LD1(QA, voff); LD1(QB, voff2); bcur += 8192u; } while (0)

#define BAR() do {                                                             \
    asm volatile("s_waitcnt lgkmcnt(0)" ::: "memory");                         \
    __builtin_amdgcn_s_barrier();                                              \
} while (0)

// body i: CB = i&1. Reads ubuf[CB]/zls[CB], writes ubuf[CB^1]/zls[CB^1].
// Wait drains exactly this body's 2 loads (4-deep rotation, no dummies).
#define BODY(QA, QB, CB, WSTR, DOISS) {                                        \
    asm volatile("s_waitcnt vmcnt(" WSTR ")" ::: "memory");                    \
    __builtin_amdgcn_sched_barrier(0);                                         \
    asm volatile("" : "+v"(QA), "+v"(QB));                                     \
    const float s0n = zls[CB];              /* next shift = z_i[0] */          \
    const f32x4* uq = (const f32x4*)ubuf[CB];                                  \
    v2f acc = {0.f, 0.f};                                                      \
    _Pragma("unroll")                                                          \
    for (int m = 0; m < 4; ++m) {                                              \
        f32x4 uu = uq[4 * kc + m];                                             \
        _Pragma("unroll")                                                      \
        for (int pp = 0; pp < 2; ++pp) {                                       \
            const int j2 = 2 * m + pp;                                         \
            unsigned int wd = (j2 < 4) ? QA[j2] : QB[j2 - 4];                  \
            v2f wp, up;                                                        \
            wp[0] = __uint_as_float(wd << 16);                                 \
            wp[1] = __uint_as_float(wd & 0xffff0000u);                         \
            up[0] = uu[2 * pp]; up[1] = uu[2 * pp + 1];                        \
            acc = __builtin_elementwise_fma(wp, up, acc);                      \
        }                                                                      \
    }                                                                          \
    float p = acc[0] + acc[1];                                                 \
    p += __shfl_xor(p, 16, 64);                                                \
    p += __shfl_xor(p, 32, 64);                                                \
    zr = __logf(p) + S;                         /* absolute z_{i+1}[bb] */     \
    const float un = __expf(zr - s0n);                                         \
    if (l < 16) ubuf[(CB) ^ 1][bb] = un;                                       \
    if (tid == 0) zls[(CB) ^ 1] = zr;                                          \
    S = s0n;                                                                   \
    if (DOISS) { ISSUE(QA, QB); }                                              \
    BAR();                                                                     \
}

    ISSUE(q0a, q0b);   // level 0
    ISSUE(q1a, q1b);   // level 1
    ISSUE(q2a, q2b);   // level 2
    ISSUE(q3a, q3b);   // level 3

    // bodies 0..55
    #pragma unroll 1
    for (int it = 0; it < 14; ++it) {
        BODY(q0a, q0b, 0, "6", 1)
        BODY(q1a, q1b, 1, "6", 1)
        BODY(q2a, q2b, 0, "6", 1)
        BODY(q3a, q3b, 1, "6", 1)
    }
    // peeled tail: bodies 56..62; last issue at body 58 (level 62); exact
    // waits leave ZERO loads in flight after body 62.
    BODY(q0a, q0b, 0, "6", 1)   // 56 -> issues L60
    BODY(q1a, q1b, 1, "6", 1)   // 57 -> issues L61
    BODY(q2a, q2b, 0, "6", 1)   // 58 -> issues L62
    BODY(q3a, q3b, 1, "6", 0)   // 59
    BODY(q0a, q0b, 0, "4", 0)   // 60
    BODY(q1a, q1b, 1, "2", 0)   // 61
    BODY(q2a, q2b, 0, "0", 0)   // 62

    // sink fold: lsexp_b( zr[b] - w_sink[b] ) + gold
    const float mm = zr - wsink;
    if (l < 16) slds[bb] = mm;
    BAR();
    if (wv == 0) {
        float m = slds[l];
        float s = 1.0f;
        #pragma unroll
        for (int d = 1; d < 64; d <<= 1) {
            float om = __shfl_xor(m, d, 64);
            float os = __shfl_xor(s, d, 64);
            float nm = fmaxf(m, om);
            s = __expf(m - nm) * s + __expf(om - nm) * os;
            m = nm;
        }
        const float vsink = m + __logf(s);
        #pragma unroll
        for (int d = 1; d < 64; d <<= 1) gs += __shfl_xor(gs, d, 64);
        if (l == 0) out[0] = gs + vsink;
    }
}

extern "C" void kernel_launch(void* const* d_in, const int* in_sizes, int n_in,
                              void* d_out, int out_size, void* d_ws, size_t ws_size,
                              hipStream_t stream) {
    const int*   g = (const int*)d_in[0];
    const float* w = (const float*)d_in[1];
    float* out     = (float*)d_out;
    unsigned int* wpk = (unsigned int*)d_ws;        // 129024 u32
    float* partial = (float*)(wpk + NPACK);         // 256 floats
    const int E = in_sizes[0] / 3;                  // 258176

    prep_kernel<<<NPB, 512, 0, stream>>>(g, w, wpk, partial, E);
    seq_kernel<<<1, 256, 0, stream>>>(w, wpk, partial, out);
}